// Round 7
// baseline (11016.702 us; speedup 1.0000x reference)
//
#include <hip/hip_runtime.h>

#define B_SZ   256
#define T_SZ   128
#define IN_DIM 512
#define EMB    1024
#define HID    1024
#define G4     4096
#define NCLS   10
#define PSTR   2560   // A-plane row stride (shorts): [x 512 | h0 1024 | h1 1024]
#define NBLK   256    // 256 blocks x 512 threads (8 waves), 1 block/CU

typedef __attribute__((ext_vector_type(8))) short short8v;
typedef __attribute__((ext_vector_type(4))) float floatx4;

__device__ __forceinline__ unsigned short bf16hi(float f) {
    union { float f; unsigned u; } v; v.f = f;
    unsigned r = v.u + 0x7fff + ((v.u >> 16) & 1);   // RNE
    return (unsigned short)(r >> 16);
}
__device__ __forceinline__ float bf2f(unsigned short b) {
    union { unsigned u; float f; } v; v.u = ((unsigned)b) << 16;
    return v.f;
}

// ---------------------------------------------------------------------------
// fp32 vector GEMM (setup only): C[M,N] = A[M,K] @ B[K,N]
// ---------------------------------------------------------------------------
template<int BM,int BN,int BK,int TM,int TN>
__global__ __launch_bounds__((BM/TM)*(BN/TN))
void gemm_f32_nn(const float* __restrict__ A, const float* __restrict__ Bm,
                 float* __restrict__ C, int M, int N, int K) {
    constexpr int THREADS = (BM/TM)*(BN/TN);
    __shared__ float As[BK][BM+4];
    __shared__ float Bs[BK][BN+4];
    const int tid  = threadIdx.x;
    const int tcol = tid % (BN/TN);
    const int trow = tid / (BN/TN);
    const int bm   = blockIdx.y * BM;
    const int bn   = blockIdx.x * BN;
    float acc[TM][TN];
#pragma unroll
    for (int i = 0; i < TM; ++i)
#pragma unroll
        for (int j = 0; j < TN; ++j) acc[i][j] = 0.f;
    for (int k0 = 0; k0 < K; k0 += BK) {
#pragma unroll
        for (int r = 0; r < BM*BK/4; r += THREADS) {
            int i  = r + tid;
            int m  = i / (BK/4);
            int kk = (i % (BK/4)) * 4;
            const float4 v = *(const float4*)(&A[(size_t)(bm+m)*K + k0 + kk]);
            As[kk+0][m]=v.x; As[kk+1][m]=v.y; As[kk+2][m]=v.z; As[kk+3][m]=v.w;
        }
#pragma unroll
        for (int r = 0; r < BK*BN/4; r += THREADS) {
            int i  = r + tid;
            int kk = i / (BN/4);
            int n4 = (i % (BN/4)) * 4;
            const float4 v = *(const float4*)(&Bm[(size_t)(k0+kk)*N + bn + n4]);
            *(float4*)(&Bs[kk][n4]) = v;
        }
        __syncthreads();
#pragma unroll
        for (int k = 0; k < BK; ++k) {
            float a[TM], b[TN];
#pragma unroll
            for (int i = 0; i < TM; ++i) a[i] = As[k][trow*TM+i];
#pragma unroll
            for (int j = 0; j < TN; ++j) b[j] = Bs[k][tcol*TN+j];
#pragma unroll
            for (int i = 0; i < TM; ++i)
#pragma unroll
                for (int j = 0; j < TN; ++j) acc[i][j] += a[i]*b[j];
        }
        __syncthreads();
    }
#pragma unroll
    for (int i = 0; i < TM; ++i)
#pragma unroll
        for (int j = 0; j < TN; ++j)
            C[(size_t)(bm+trow*TM+i)*N + bn + tcol*TN + j] = acc[i][j];
}

// ---------------------------------------------------------------------------
// Weight swizzle to frag-major hi/lo, gate-interleaved columns.
// Output col n (0..4095): unit j=n>>2, gate q=n&3 -> source row q*1024 + j.
// K split: kf < kf0 from M0 (width K0), else from M1 (width K1).
// frag (cf, kf): dst[((cf*kfcnt+kf)*2+p)*512 + l*8 + j]
// ---------------------------------------------------------------------------
__global__ void swz2(const float* __restrict__ M0, int K0, int kf0,
                     const float* __restrict__ M1, int K1, int kfcnt,
                     unsigned short* __restrict__ dst) {
    int gid = blockIdx.x * 256 + threadIdx.x;
    int l   = gid & 63;
    int kf  = (gid >> 6) % kfcnt;
    int cf  = gid / (64 * kfcnt);
    int n   = cf*16 + (l & 15);
    int row = ((n & 3) << 10) + (n >> 2);
    const float* src; int kk = (l >> 4) * 8;
    if (kf < kf0) { src = M0 + (size_t)row * K0; kk += kf * 32; }
    else          { src = M1 + (size_t)row * K1; kk += (kf - kf0) * 32; }
    short8v vh, vl;
#pragma unroll
    for (int j = 0; j < 8; ++j) {
        float f = src[kk + j];
        unsigned short h = bf16hi(f);
        vh[j] = (short)h;
        vl[j] = (short)bf16hi(f - bf2f(h));
    }
    size_t base = ((size_t)(cf * kfcnt + kf) * 2) * 512 + (size_t)l * 8;
    *(short8v*)(dst + base)       = vh;
    *(short8v*)(dst + base + 512) = vl;
}

// bcombI[4j+q] = b_ih0 + b_hh0 + W_ih0[row,:] . b_enc   (row = q*1024+j)
__global__ void build_bcombI(const float* __restrict__ W_ih0, const float* __restrict__ b_enc,
                             const float* __restrict__ b_ih0, const float* __restrict__ b_hh0,
                             float* __restrict__ bcombI) {
    int row  = blockIdx.x * 4 + (threadIdx.x >> 6);
    int lane = threadIdx.x & 63;
    const float* w = W_ih0 + (size_t)row * EMB;
    float s = 0.f;
    for (int k = lane; k < EMB; k += 64) s += w[k] * b_enc[k];
#pragma unroll
    for (int o = 32; o > 0; o >>= 1) s += __shfl_down(s, o);
    if (lane == 0) {
        int n = ((row & 1023) << 2) | (row >> 10);
        bcombI[n] = s + b_ih0[row] + b_hh0[row];
    }
}

__global__ void addvI(const float* __restrict__ a, const float* __restrict__ b,
                      float* __restrict__ o) {
    int i = blockIdx.x * 256 + threadIdx.x;
    int n = ((i & 1023) << 2) | (i >> 10);
    o[n] = a[i] + b[i];
}

// ---------------------------------------------------------------------------
// Persistent LSTM kernel. 256 blocks x 512 threads (8 waves), 1 block/CU.
// XCD-aware remap: cg = (bid&7)*16 + (bid>>4), rg = (bid>>3)&1 — the two
// row-group blocks sharing a 64-col weight stripe are bids (b, b+8) => same
// XCD => second weight read hits that XCD's L2.
//   cg < 64  : gates0(t),   A = plane cols 0..1535  (x_t | h0), 48 kf
//   cg >= 64 : gates1(t-1), A = plane cols 512..2559 (h0 | h1), 64 kf
// 8 waves = 2 K-groups x (2 rowhalf x 2 colhalf); K-group partials summed
// via gtile. NO LDS / NO barriers in the K-loop: each wave loads its A and B
// fragments global->VGPR with a 2-slice-deep register pipeline; compiler's
// counted vmcnt lets loads span slices. 3 syncthreads per phase total.
// One grid barrier per phase; planes parity-double-buffered.
// ---------------------------------------------------------------------------
__device__ __forceinline__ void gridbar(unsigned* bar, unsigned target, int tid) {
    __syncthreads();
    if (tid == 0) {
        __threadfence();
        atomicAdd(bar, 1u);
        while (__hip_atomic_load(bar, __ATOMIC_RELAXED, __HIP_MEMORY_SCOPE_AGENT) < target)
            __builtin_amdgcn_s_sleep(1);
        __threadfence();
    }
    __syncthreads();
}

__device__ __forceinline__ void store_xz(unsigned short* ph, unsigned short* pl,
                                         int bid, int tid, float2 xv) {
    unsigned short h0 = bf16hi(xv.x), h1 = bf16hi(xv.y);
    ushort2 hh; hh.x = h0; hh.y = h1;
    ushort2 lv; lv.x = bf16hi(xv.x - bf2f(h0)); lv.y = bf16hi(xv.y - bf2f(h1));
    size_t o = (size_t)bid * PSTR + tid * 2;
    *(ushort2*)(ph + o) = hh;
    *(ushort2*)(pl + o) = lv;
}

struct SliceRegs {
    short8v ah[4], al[4];          // A fragments (4 m-frags, hi/lo)
    short8v bh0, bl0, bh1, bl1;    // B fragments (2 cf, hi/lo)
};

__global__ __launch_bounds__(512, 2)
void lstm_persist(const float* __restrict__ x,
                  const unsigned short* __restrict__ WLz,
                  const unsigned short* __restrict__ WRz,
                  const float* __restrict__ biasLI, const float* __restrict__ biasRI,
                  unsigned short* __restrict__ p0h, unsigned short* __restrict__ p0l,
                  unsigned short* __restrict__ p1h, unsigned short* __restrict__ p1l,
                  const float* __restrict__ Wcls, const float* __restrict__ bcls,
                  float* __restrict__ out, unsigned* __restrict__ bar) {
    __shared__ float gtile[128][68];                 // 34.8 KB

    const int tid = threadIdx.x, bid = blockIdx.x;
    const int w = tid >> 6, l = tid & 63;
    const int kgrp = w >> 2, sub = w & 3;
    const int rowhalf = sub & 1, colhalf = sub >> 1;
    // XCD-aware block remap (bid, bid+8 share cg => same XCD L2)
    const int cg = (bid & 7) * 16 + (bid >> 4);
    const int rg = (bid >> 3) & 1;
    const bool is_left = (cg < 64);
    const int cgl = is_left ? cg : cg - 64;
    const int SMAX = is_left ? 24 : 32;              // kf per K-group
    const int kfcnt = 2 * SMAX;
    const int acol0 = is_left ? 0 : 512;
    const int hcol0 = is_left ? 512 : 1536;
    const int r0 = rg * 128;
    const unsigned short* Bz = is_left ? WLz : WRz;
    const float* biasI = is_left ? biasLI : biasRI;

    const int cf0 = cgl*4 + colhalf*2;
    const unsigned short* bp0 = Bz + ((size_t)cf0     * kfcnt) * 1024 + (size_t)l * 8;
    const unsigned short* bp1 = Bz + ((size_t)(cf0+1) * kfcnt) * 1024 + (size_t)l * 8;
    const int kbase = kgrp * SMAX;

    const int arow = r0 + rowhalf*64 + (l & 15);     // + m*16
    const int akol = (l >> 4) * 8;                   // + acol0 + kf*32

    float bias0 = 0.f, bias1 = 0.f;
    if (kgrp == 0) {
        int cA = cgl*64 + colhalf*32 + (l & 15);
        bias0 = biasI[cA]; bias1 = biasI[cA + 16];
    }

    unsigned short* PH[2] = {p0h, p1h};
    unsigned short* PL[2] = {p0l, p1l};

    float cst[4];
#pragma unroll
    for (int i = 0; i < 4; ++i) cst[i] = 0.f;

    unsigned target = 0;

    if (tid < 256) {   // stage x(0) into plane 0 (bid == batch row)
        float2 xv = *(const float2*)&x[((size_t)bid * T_SZ) * IN_DIM + tid * 2];
        store_xz(p0h, p0l, bid, tid, xv);
    }
    target += NBLK; gridbar(bar, target, tid);

    for (int t = 0; t <= T_SZ; ++t) {
        const int cur = t & 1, nxt = cur ^ 1;
        const bool conv = (t < T_SZ - 1) && (tid < 256);
        float2 xv;
        if (conv) xv = *(const float2*)&x[((size_t)bid * T_SZ + t + 1) * IN_DIM + tid * 2];

        const bool active = is_left ? (t < T_SZ) : (t >= 1);
        if (active) {
            const unsigned short* ph  = PH[cur];
            const unsigned short* plo = PL[cur];

            auto load_slice = [&](int s, SliceRegs& S) {
                const int kf = kbase + s;
                const size_t ko = (size_t)acol0 + (size_t)kf * 32 + akol;
#pragma unroll
                for (int m = 0; m < 4; ++m) {
                    size_t o = (size_t)(arow + m*16) * PSTR + ko;
                    S.ah[m] = *(const short8v*)(ph + o);
                    S.al[m] = *(const short8v*)(plo + o);
                }
                const unsigned short* p0 = bp0 + (size_t)kf * 1024;
                const unsigned short* p1 = bp1 + (size_t)kf * 1024;
                S.bh0 = *(const short8v*)p0; S.bl0 = *(const short8v*)(p0 + 512);
                S.bh1 = *(const short8v*)p1; S.bl1 = *(const short8v*)(p1 + 512);
            };

            floatx4 acc[4][2];
#pragma unroll
            for (int m = 0; m < 4; ++m) {
                acc[m][0] = (floatx4){bias0, bias0, bias0, bias0};
                acc[m][1] = (floatx4){bias1, bias1, bias1, bias1};
            }

            auto do_mfma = [&](SliceRegs& S) {
#pragma unroll
                for (int m = 0; m < 4; ++m) {
                    acc[m][0] = __builtin_amdgcn_mfma_f32_16x16x32_bf16(S.ah[m], S.bh0, acc[m][0], 0, 0, 0);
                    acc[m][0] = __builtin_amdgcn_mfma_f32_16x16x32_bf16(S.ah[m], S.bl0, acc[m][0], 0, 0, 0);
                    acc[m][0] = __builtin_amdgcn_mfma_f32_16x16x32_bf16(S.al[m], S.bh0, acc[m][0], 0, 0, 0);
                    acc[m][1] = __builtin_amdgcn_mfma_f32_16x16x32_bf16(S.ah[m], S.bh1, acc[m][1], 0, 0, 0);
                    acc[m][1] = __builtin_amdgcn_mfma_f32_16x16x32_bf16(S.ah[m], S.bl1, acc[m][1], 0, 0, 0);
                    acc[m][1] = __builtin_amdgcn_mfma_f32_16x16x32_bf16(S.al[m], S.bh1, acc[m][1], 0, 0, 0);
                }
            };

            SliceRegs SA, SB;
            load_slice(0, SA);
            load_slice(1, SB);
            for (int s2 = 0; s2 < SMAX; s2 += 2) {
                do_mfma(SA);
                if (s2 + 2 < SMAX) load_slice(s2 + 2, SA);
                do_mfma(SB);
                if (s2 + 3 < SMAX) load_slice(s2 + 3, SB);
            }

            __syncthreads();
            // partial-sum reduction: group0 writes (bias pre-seeded), group1 adds
            if (kgrp == 0) {
#pragma unroll
                for (int m = 0; m < 4; ++m)
#pragma unroll
                    for (int c = 0; c < 2; ++c) {
                        int col = colhalf*32 + c*16 + (l & 15);
#pragma unroll
                        for (int jj = 0; jj < 4; ++jj)
                            gtile[rowhalf*64 + m*16 + ((l >> 4)*4) + jj][col] = acc[m][c][jj];
                    }
            }
            __syncthreads();
            if (kgrp == 1) {
#pragma unroll
                for (int m = 0; m < 4; ++m)
#pragma unroll
                    for (int c = 0; c < 2; ++c) {
                        int col = colhalf*32 + c*16 + (l & 15);
#pragma unroll
                        for (int jj = 0; jj < 4; ++jj)
                            gtile[rowhalf*64 + m*16 + ((l >> 4)*4) + jj][col] += acc[m][c][jj];
                    }
            }
            __syncthreads();

            // LSTM cell: 16 units x 128 rows, 4 cells/thread, c-state in regs
            {
                int u = tid & 15, rq = tid >> 4;
                unsigned short* nh = PH[nxt];
                unsigned short* nl = PL[nxt];
#pragma unroll
                for (int i = 0; i < 4; ++i) {
                    int r = rq*4 + i;
                    float4 gq = *(const float4*)&gtile[r][4*u];
                    float ii = 1.f / (1.f + expf(-gq.x));
                    float ff = 1.f / (1.f + expf(-gq.y));
                    float gg = tanhf(gq.z);
                    float oo = 1.f / (1.f + expf(-gq.w));
                    float cn = ff * cst[i] + ii * gg;
                    cst[i] = cn;
                    float h = oo * tanhf(cn);
                    unsigned short hh = bf16hi(h);
                    size_t o = (size_t)(r0 + r) * PSTR + hcol0 + cgl*16 + u;
                    nh[o] = hh;
                    nl[o] = bf16hi(h - bf2f(hh));
                }
            }
        }

        if (conv) store_xz(PH[nxt], PL[nxt], bid, tid, xv);
        target += NBLK; gridbar(bar, target, tid);
    }

    // classifier: block bid -> batch row bid; h1 = plane[(T+1)&1] cols 1536..2559
    {
        const unsigned short* hh = PH[(T_SZ + 1) & 1];
        const unsigned short* hl = PL[(T_SZ + 1) & 1];
        float part[NCLS];
#pragma unroll
        for (int n = 0; n < NCLS; ++n) part[n] = 0.f;
        for (int k = tid; k < HID; k += 512) {
            size_t o = (size_t)bid * PSTR + 1536 + k;
            float hv = bf2f(hh[o]) + bf2f(hl[o]);
#pragma unroll
            for (int n = 0; n < NCLS; ++n) part[n] += hv * Wcls[(size_t)n * HID + k];
        }
        float* red = (float*)gtile;
        for (int n = 0; n < NCLS; ++n) {
            red[tid] = part[n];
            __syncthreads();
            for (int s = 256; s > 0; s >>= 1) {
                if (tid < s) red[tid] += red[tid + s];
                __syncthreads();
            }
            if (tid == 0) out[(size_t)bid * NCLS + n] = red[0] + bcls[n];
            __syncthreads();
        }
    }
}

extern "C" void kernel_launch(void* const* d_in, const int* in_sizes, int n_in,
                              void* d_out, int out_size, void* d_ws, size_t ws_size,
                              hipStream_t stream) {
    const float* x      = (const float*)d_in[0];
    const float* W_enc  = (const float*)d_in[1];
    const float* b_enc  = (const float*)d_in[2];
    const float* W_ih0  = (const float*)d_in[3];
    const float* W_hh0  = (const float*)d_in[4];
    const float* b_ih0  = (const float*)d_in[5];
    const float* b_hh0  = (const float*)d_in[6];
    const float* W_ih1  = (const float*)d_in[7];
    const float* W_hh1  = (const float*)d_in[8];
    const float* b_ih1  = (const float*)d_in[9];
    const float* b_hh1  = (const float*)d_in[10];
    const float* W_cls  = (const float*)d_in[11];
    const float* b_cls  = (const float*)d_in[12];
    float* out = (float*)d_out;

    float* ws = (float*)d_ws;
    size_t off = 0;
    unsigned short* WLz    = (unsigned short*)(ws + off); off += (size_t)G4 * 1536 * 2 / 2;
    unsigned short* WRz    = (unsigned short*)(ws + off); off += (size_t)G4 * 2048 * 2 / 2;
    float*          Wcomb  = ws + off;                    off += (size_t)G4 * IN_DIM;
    float*          biasLI = ws + off;                    off += G4;
    float*          biasRI = ws + off;                    off += G4;
    unsigned short* planes = (unsigned short*)(ws + off); off += (size_t)4 * B_SZ * PSTR / 2;
    unsigned*       bar    = (unsigned*)(ws + off);       off += 64;

    unsigned short* p0h = planes;
    unsigned short* p0l = p0h + (size_t)B_SZ * PSTR;
    unsigned short* p1h = p0l + (size_t)B_SZ * PSTR;
    unsigned short* p1l = p1h + (size_t)B_SZ * PSTR;

    // --- setup ---
    gemm_f32_nn<128,128,16,8,8><<<dim3(IN_DIM/128, G4/128), 256, 0, stream>>>(
        W_ih0, W_enc, Wcomb, G4, IN_DIM, EMB);
    build_bcombI<<<G4/4, 256, 0, stream>>>(W_ih0, b_enc, b_ih0, b_hh0, biasLI);
    addvI<<<G4/256, 256, 0, stream>>>(b_ih1, b_hh1, biasRI);
    // WLz: [Wcomb(16 kf) | W_hh0(32 kf)] ; WRz: [W_ih1(32 kf) | W_hh1(32 kf)]
    swz2<<<64*48, 256, 0, stream>>>(Wcomb, IN_DIM, 16, W_hh0, HID, 48, WLz);
    swz2<<<64*64, 256, 0, stream>>>(W_ih1, HID, 32, W_hh1, HID, 64, WRz);
    hipMemsetAsync(planes, 0, (size_t)4 * B_SZ * PSTR * 2, stream);
    hipMemsetAsync(bar, 0, sizeof(unsigned), stream);

    // --- the whole recurrence in one kernel ---
    lstm_persist<<<NBLK, 512, 0, stream>>>(
        x, WLz, WRz, biasLI, biasRI,
        p0h, p0l, p1h, p1l, W_cls, b_cls, out, bar);
}

// Round 9
// 9103.374 us; speedup vs baseline: 1.2102x; 1.2102x over previous
//
#include <hip/hip_runtime.h>

#define B_SZ   256
#define T_SZ   128
#define IN_DIM 512
#define EMB    1024
#define HID    1024
#define G4     4096
#define NCLS   10
#define PSTR   2560   // A-plane row stride (shorts): [x 512 | h0 1024 | h1 1024]
#define NBLK   256    // 256 blocks x 512 threads (8 waves), 1 block/CU

typedef __attribute__((ext_vector_type(8))) short short8v;
typedef __attribute__((ext_vector_type(4))) float floatx4;

__device__ __forceinline__ unsigned short bf16hi(float f) {
    union { float f; unsigned u; } v; v.f = f;
    unsigned r = v.u + 0x7fff + ((v.u >> 16) & 1);   // RNE
    return (unsigned short)(r >> 16);
}
__device__ __forceinline__ float bf2f(unsigned short b) {
    union { unsigned u; float f; } v; v.u = ((unsigned)b) << 16;
    return v.f;
}

#define LGKM0_BAR()  do { \
    asm volatile("s_waitcnt lgkmcnt(0)" ::: "memory"); \
    __builtin_amdgcn_sched_barrier(0); \
    __builtin_amdgcn_s_barrier(); \
    __builtin_amdgcn_sched_barrier(0); } while (0)

// ---------------------------------------------------------------------------
// fp32 vector GEMM (setup only): C[M,N] = A[M,K] @ B[K,N]
// ---------------------------------------------------------------------------
template<int BM,int BN,int BK,int TM,int TN>
__global__ __launch_bounds__((BM/TM)*(BN/TN))
void gemm_f32_nn(const float* __restrict__ A, const float* __restrict__ Bm,
                 float* __restrict__ C, int M, int N, int K) {
    constexpr int THREADS = (BM/TM)*(BN/TN);
    __shared__ float As[BK][BM+4];
    __shared__ float Bs[BK][BN+4];
    const int tid  = threadIdx.x;
    const int tcol = tid % (BN/TN);
    const int trow = tid / (BN/TN);
    const int bm   = blockIdx.y * BM;
    const int bn   = blockIdx.x * BN;
    float acc[TM][TN];
#pragma unroll
    for (int i = 0; i < TM; ++i)
#pragma unroll
        for (int j = 0; j < TN; ++j) acc[i][j] = 0.f;
    for (int k0 = 0; k0 < K; k0 += BK) {
#pragma unroll
        for (int r = 0; r < BM*BK/4; r += THREADS) {
            int i  = r + tid;
            int m  = i / (BK/4);
            int kk = (i % (BK/4)) * 4;
            const float4 v = *(const float4*)(&A[(size_t)(bm+m)*K + k0 + kk]);
            As[kk+0][m]=v.x; As[kk+1][m]=v.y; As[kk+2][m]=v.z; As[kk+3][m]=v.w;
        }
#pragma unroll
        for (int r = 0; r < BK*BN/4; r += THREADS) {
            int i  = r + tid;
            int kk = i / (BN/4);
            int n4 = (i % (BN/4)) * 4;
            const float4 v = *(const float4*)(&Bm[(size_t)(k0+kk)*N + bn + n4]);
            *(float4*)(&Bs[kk][n4]) = v;
        }
        __syncthreads();
#pragma unroll
        for (int k = 0; k < BK; ++k) {
            float a[TM], b[TN];
#pragma unroll
            for (int i = 0; i < TM; ++i) a[i] = As[k][trow*TM+i];
#pragma unroll
            for (int j = 0; j < TN; ++j) b[j] = Bs[k][tcol*TN+j];
#pragma unroll
            for (int i = 0; i < TM; ++i)
#pragma unroll
                for (int j = 0; j < TN; ++j) acc[i][j] += a[i]*b[j];
        }
        __syncthreads();
    }
#pragma unroll
    for (int i = 0; i < TM; ++i)
#pragma unroll
        for (int j = 0; j < TN; ++j)
            C[(size_t)(bm+trow*TM+i)*N + bn + tcol*TN + j] = acc[i][j];
}

// ---------------------------------------------------------------------------
// Weight swizzle to frag-major hi/lo, gate-interleaved columns.
// Output col n (0..4095): unit j=n>>2, gate q=n&3 -> source row q*1024 + j.
// K split: kf < kf0 from M0 (width K0), else from M1 (width K1).
// frag (cf, kf): dst[((cf*kfcnt+kf)*2+p)*512 + l*8 + j]
// ---------------------------------------------------------------------------
__global__ void swz2(const float* __restrict__ M0, int K0, int kf0,
                     const float* __restrict__ M1, int K1, int kfcnt,
                     unsigned short* __restrict__ dst) {
    int gid = blockIdx.x * 256 + threadIdx.x;
    int l   = gid & 63;
    int kf  = (gid >> 6) % kfcnt;
    int cf  = gid / (64 * kfcnt);
    int n   = cf*16 + (l & 15);
    int row = ((n & 3) << 10) + (n >> 2);
    const float* src; int kk = (l >> 4) * 8;
    if (kf < kf0) { src = M0 + (size_t)row * K0; kk += kf * 32; }
    else          { src = M1 + (size_t)row * K1; kk += (kf - kf0) * 32; }
    short8v vh, vl;
#pragma unroll
    for (int j = 0; j < 8; ++j) {
        float f = src[kk + j];
        unsigned short h = bf16hi(f);
        vh[j] = (short)h;
        vl[j] = (short)bf16hi(f - bf2f(h));
    }
    size_t base = ((size_t)(cf * kfcnt + kf) * 2) * 512 + (size_t)l * 8;
    *(short8v*)(dst + base)       = vh;
    *(short8v*)(dst + base + 512) = vl;
}

// bcombI[4j+q] = b_ih0 + b_hh0 + W_ih0[row,:] . b_enc   (row = q*1024+j)
__global__ void build_bcombI(const float* __restrict__ W_ih0, const float* __restrict__ b_enc,
                             const float* __restrict__ b_ih0, const float* __restrict__ b_hh0,
                             float* __restrict__ bcombI) {
    int row  = blockIdx.x * 4 + (threadIdx.x >> 6);
    int lane = threadIdx.x & 63;
    const float* w = W_ih0 + (size_t)row * EMB;
    float s = 0.f;
    for (int k = lane; k < EMB; k += 64) s += w[k] * b_enc[k];
#pragma unroll
    for (int o = 32; o > 0; o >>= 1) s += __shfl_down(s, o);
    if (lane == 0) {
        int n = ((row & 1023) << 2) | (row >> 10);
        bcombI[n] = s + b_ih0[row] + b_hh0[row];
    }
}

__global__ void addvI(const float* __restrict__ a, const float* __restrict__ b,
                      float* __restrict__ o) {
    int i = blockIdx.x * 256 + threadIdx.x;
    int n = ((i & 1023) << 2) | (i >> 10);
    o[n] = a[i] + b[i];
}

// ---------------------------------------------------------------------------
// Persistent LSTM kernel, 3-pass split-bf16 (proven numerics), counted-wait
// K-loop (no vmcnt(0) barriers). 256 blocks x 512 threads (8 waves), 1/CU.
// XCD-dedup map: xcd=bid&7, idx=bid>>3; idx<16 -> LEFT else RIGHT;
// cgl = xcd*8 + (idx&7), rg = (idx&15)>>3. Per-XCD weight slice L2-local.
//   LEFT : gates0(t),   A = plane cols 0..1535  (x_t|h0), kf 48
//   RIGHT: gates1(t-1), A = plane cols 512..2559 (h0|h1), kf 64
// 8 waves = 2 kgroups x (2 rowhalf x 2 colhalf); kgroup g handles kf range
// [g*SMAXH, (g+1)*SMAXH); partials summed via gtile. Stage = 1 kf:
//   A: global->reg 2 stages ahead, reg->LDS(dbuf) 1 ahead, LDS->MFMA.
//   B: global->reg (even/odd named sets), reissued after consumption.
// Per stage: raw s_barrier + lgkmcnt(0) only — global loads stay in flight
// across barriers (counted vmcnt by compiler). LDS: A dbuf 64KB ∪ gtile.
// ---------------------------------------------------------------------------
__device__ __forceinline__ void gridbar(unsigned* bar, unsigned target, int tid) {
    __syncthreads();
    if (tid == 0) {
        __threadfence();
        atomicAdd(bar, 1u);
        while (__hip_atomic_load(bar, __ATOMIC_RELAXED, __HIP_MEMORY_SCOPE_AGENT) < target)
            __builtin_amdgcn_s_sleep(1);
        __threadfence();
    }
    __syncthreads();
}

__device__ __forceinline__ void store_xz(unsigned short* ph, unsigned short* pl,
                                         int bid, int tid, float2 xv) {
    unsigned short h0 = bf16hi(xv.x), h1 = bf16hi(xv.y);
    ushort2 hh; hh.x = h0; hh.y = h1;
    ushort2 lv; lv.x = bf16hi(xv.x - bf2f(h0)); lv.y = bf16hi(xv.y - bf2f(h1));
    size_t o = (size_t)bid * PSTR + tid * 2;
    *(ushort2*)(ph + o) = hh;
    *(ushort2*)(pl + o) = lv;
}

__global__ __launch_bounds__(512, 1)
void lstm_persist(const float* __restrict__ x,
                  const unsigned short* __restrict__ WLz,
                  const unsigned short* __restrict__ WRz,
                  const float* __restrict__ biasLI, const float* __restrict__ biasRI,
                  unsigned short* __restrict__ p0h, unsigned short* __restrict__ p0l,
                  unsigned short* __restrict__ p1h, unsigned short* __restrict__ p1l,
                  const float* __restrict__ Wcls, const float* __restrict__ bcls,
                  float* __restrict__ out, unsigned* __restrict__ bar) {
    // A dbuf: [buf2][kg2][mf8][pl2][64][8] shorts = 64KB. gtile overlays it.
    __shared__ unsigned short AslH[32768];
    float (*gtile)[68] = (float (*)[68])AslH;        // 128x68 f32 = 34.8KB

    const int tid = threadIdx.x, bid = blockIdx.x;
    const int w = tid >> 6, l = tid & 63;
    const int kgrp = w >> 2, sub = w & 3;
    const int rowhalf = sub & 1, colhalf = sub >> 1;
    // XCD-dedup block map (bijective)
    const int xcd = bid & 7;
    const int idx = bid >> 3;
    const bool is_left = (idx < 16);
    const int i2 = is_left ? idx : idx - 16;
    const int cgl = xcd * 8 + (i2 & 7);
    const int rg  = i2 >> 3;
    const int kfcnt = is_left ? 48 : 64;
    const int SMAXH = is_left ? 24 : 32;     // kf per kgroup = NS stages
    const int acol0 = is_left ? 0 : 512;
    const int hcol0 = is_left ? 512 : 1536;
    const int r0 = rg * 128;
    const unsigned short* Bz = is_left ? WLz : WRz;
    const float* biasI = is_left ? biasLI : biasRI;
    const int kf_base = kgrp * SMAXH;
    const int NS = SMAXH;

    const int cf0 = cgl*4 + colhalf*2;
    const unsigned short* bp0 = Bz + ((size_t)cf0     * kfcnt) * 1024 + (size_t)l * 8;
    const unsigned short* bp1 = Bz + ((size_t)(cf0+1) * kfcnt) * 1024 + (size_t)l * 8;

    float bias0 = 0.f, bias1 = 0.f;
    if (kgrp == 0) {
        int cA = cgl*64 + colhalf*32 + (l & 15);
        bias0 = biasI[cA]; bias1 = biasI[cA + 16];
    }

    unsigned short* PH[2] = {p0h, p1h};
    unsigned short* PL[2] = {p0l, p1l};

    float cst[4];
#pragma unroll
    for (int i = 0; i < 4; ++i) cst[i] = 0.f;

    unsigned target = 0;

    if (tid < 256) {   // stage x(0) into plane 0 (bid == batch row)
        float2 xv = *(const float2*)&x[((size_t)bid * T_SZ) * IN_DIM + tid * 2];
        store_xz(p0h, p0l, bid, tid, xv);
    }
    target += NBLK; gridbar(bar, target, tid);

    for (int t = 0; t <= T_SZ; ++t) {
        const int cur = t & 1, nxt = cur ^ 1;
        const bool conv = (t < T_SZ - 1) && (tid < 256);
        float2 xv;
        if (conv) xv = *(const float2*)&x[((size_t)bid * T_SZ + t + 1) * IN_DIM + tid * 2];

        const bool active = is_left ? (t < T_SZ) : (t >= 1);
        if (active) {
            const unsigned short* ph  = PH[cur];
            const unsigned short* plo = PL[cur];

            auto loadA = [&](int s, short8v (&r)[4]) {
#pragma unroll
                for (int i = 0; i < 4; ++i) {
                    int seg = w*4 + i;
                    int kg = seg >> 4, mf = (seg >> 1) & 7, pl = seg & 1;
                    int kf = kg * SMAXH + s;
                    const unsigned short* p = pl ? plo : ph;
                    size_t o = (size_t)(r0 + mf*16 + (l & 15)) * PSTR
                             + acol0 + kf*32 + ((l >> 4) * 8);
                    r[i] = *(const short8v*)(p + o);
                }
            };
            auto writeA = [&](int buf, short8v (&r)[4]) {
#pragma unroll
                for (int i = 0; i < 4; ++i) {
                    int seg = w*4 + i;
                    int kg = seg >> 4, mf = (seg >> 1) & 7, pl = seg & 1;
                    *(short8v*)(AslH + (size_t)((((buf*2 + kg)*8 + mf)*2 + pl)*64 + l)*8) = r[i];
                }
            };
            auto loadB = [&](int s, short8v (&b)[4]) {
                int kf = kf_base + s;
                const unsigned short* q0 = bp0 + (size_t)kf * 1024;
                const unsigned short* q1 = bp1 + (size_t)kf * 1024;
                b[0] = *(const short8v*)q0; b[1] = *(const short8v*)(q0 + 512);
                b[2] = *(const short8v*)q1; b[3] = *(const short8v*)(q1 + 512);
            };

            floatx4 acc[4][2];
#pragma unroll
            for (int m = 0; m < 4; ++m) {
                acc[m][0] = (floatx4){bias0, bias0, bias0, bias0};
                acc[m][1] = (floatx4){bias1, bias1, bias1, bias1};
            }

            auto mfmaStage = [&](int buf, short8v (&b)[4]) {
                short8v ah[4], al[4];
#pragma unroll
                for (int m = 0; m < 4; ++m) {
                    size_t base = (size_t)((((buf*2 + kgrp)*8 + rowhalf*4 + m)*2)*64 + l)*8;
                    ah[m] = *(const short8v*)(AslH + base);
                    al[m] = *(const short8v*)(AslH + base + 512);
                }
#pragma unroll
                for (int m = 0; m < 4; ++m) {
                    acc[m][0] = __builtin_amdgcn_mfma_f32_16x16x32_bf16(ah[m], b[0], acc[m][0], 0, 0, 0);
                    acc[m][0] = __builtin_amdgcn_mfma_f32_16x16x32_bf16(ah[m], b[1], acc[m][0], 0, 0, 0);
                    acc[m][0] = __builtin_amdgcn_mfma_f32_16x16x32_bf16(al[m], b[0], acc[m][0], 0, 0, 0);
                    acc[m][1] = __builtin_amdgcn_mfma_f32_16x16x32_bf16(ah[m], b[2], acc[m][1], 0, 0, 0);
                    acc[m][1] = __builtin_amdgcn_mfma_f32_16x16x32_bf16(ah[m], b[3], acc[m][1], 0, 0, 0);
                    acc[m][1] = __builtin_amdgcn_mfma_f32_16x16x32_bf16(al[m], b[2], acc[m][1], 0, 0, 0);
                }
            };

            short8v rA[4], rB[4], bE[4], bO[4];
            // prologue: A(0),B(0),A(1),B(1) in flight; A(0)->LDS buf0
            loadA(0, rA); loadB(0, bE);
            loadA(1, rB); loadB(1, bO);
            writeA(0, rA);                 // compiler emits counted vmcnt for rA
            LGKM0_BAR();

            for (int s = 0; s < NS; s += 2) {
                // even stage s: compute buf0, write A(s+1)->buf1
                if (s + 2 < NS) loadA(s + 2, rA);
                writeA(1, rB);
                mfmaStage(0, bE);
                if (s + 2 < NS) loadB(s + 2, bE);
                LGKM0_BAR();
                // odd stage s+1: compute buf1, write A(s+2)->buf0
                if (s + 3 < NS) loadA(s + 3, rB);
                if (s + 2 < NS) writeA(0, rA);
                mfmaStage(1, bO);
                if (s + 3 < NS) loadB(s + 3, bO);
                LGKM0_BAR();
            }
            __syncthreads();   // full drain before gtile overlays A bufs

            // kgroup partial-sum via gtile
            if (kgrp == 0) {
#pragma unroll
                for (int m = 0; m < 4; ++m)
#pragma unroll
                    for (int c = 0; c < 2; ++c) {
                        int col = colhalf*32 + c*16 + (l & 15);
#pragma unroll
                        for (int jj = 0; jj < 4; ++jj)
                            gtile[rowhalf*64 + m*16 + ((l >> 4)*4) + jj][col] = acc[m][c][jj];
                    }
            }
            __syncthreads();
            if (kgrp == 1) {
#pragma unroll
                for (int m = 0; m < 4; ++m)
#pragma unroll
                    for (int c = 0; c < 2; ++c) {
                        int col = colhalf*32 + c*16 + (l & 15);
#pragma unroll
                        for (int jj = 0; jj < 4; ++jj)
                            gtile[rowhalf*64 + m*16 + ((l >> 4)*4) + jj][col] += acc[m][c][jj];
                    }
            }
            __syncthreads();

            // LSTM cell: 16 units x 128 rows, 4 cells/thread, c-state in regs
            {
                int u = tid & 15, rq = tid >> 4;
                unsigned short* nh = PH[nxt];
                unsigned short* nl = PL[nxt];
#pragma unroll
                for (int i = 0; i < 4; ++i) {
                    int r = rq*4 + i;
                    float4 gq = *(const float4*)&gtile[r][4*u];
                    float ii = 1.f / (1.f + expf(-gq.x));
                    float ff = 1.f / (1.f + expf(-gq.y));
                    float gg = tanhf(gq.z);
                    float oo = 1.f / (1.f + expf(-gq.w));
                    float cn = ff * cst[i] + ii * gg;
                    cst[i] = cn;
                    float h = oo * tanhf(cn);
                    unsigned short hh = bf16hi(h);
                    size_t o = (size_t)(r0 + r) * PSTR + hcol0 + cgl*16 + u;
                    nh[o] = hh;
                    nl[o] = bf16hi(h - bf2f(hh));
                }
            }
        }

        if (conv) store_xz(PH[nxt], PL[nxt], bid, tid, xv);
        target += NBLK; gridbar(bar, target, tid);
    }

    // classifier: block bid -> batch row bid; h1 = plane[(T+1)&1] cols 1536..2559
    {
        const unsigned short* hh = PH[(T_SZ + 1) & 1];
        const unsigned short* hl = PL[(T_SZ + 1) & 1];
        float part[NCLS];
#pragma unroll
        for (int n = 0; n < NCLS; ++n) part[n] = 0.f;
        for (int k = tid; k < HID; k += 512) {
            size_t o = (size_t)bid * PSTR + 1536 + k;
            float hv = bf2f(hh[o]) + bf2f(hl[o]);
#pragma unroll
            for (int n = 0; n < NCLS; ++n) part[n] += hv * Wcls[(size_t)n * HID + k];
        }
        float* red = (float*)AslH;
        for (int n = 0; n < NCLS; ++n) {
            red[tid] = part[n];
            __syncthreads();
            for (int s = 256; s > 0; s >>= 1) {
                if (tid < s) red[tid] += red[tid + s];
                __syncthreads();
            }
            if (tid == 0) out[(size_t)bid * NCLS + n] = red[0] + bcls[n];
            __syncthreads();
        }
    }
}

extern "C" void kernel_launch(void* const* d_in, const int* in_sizes, int n_in,
                              void* d_out, int out_size, void* d_ws, size_t ws_size,
                              hipStream_t stream) {
    const float* x      = (const float*)d_in[0];
    const float* W_enc  = (const float*)d_in[1];
    const float* b_enc  = (const float*)d_in[2];
    const float* W_ih0  = (const float*)d_in[3];
    const float* W_hh0  = (const float*)d_in[4];
    const float* b_ih0  = (const float*)d_in[5];
    const float* b_hh0  = (const float*)d_in[6];
    const float* W_ih1  = (const float*)d_in[7];
    const float* W_hh1  = (const float*)d_in[8];
    const float* b_ih1  = (const float*)d_in[9];
    const float* b_hh1  = (const float*)d_in[10];
    const float* W_cls  = (const float*)d_in[11];
    const float* b_cls  = (const float*)d_in[12];
    float* out = (float*)d_out;

    float* ws = (float*)d_ws;
    size_t off = 0;
    unsigned short* WLz    = (unsigned short*)(ws + off); off += (size_t)G4 * 1536 * 2 / 2;
    unsigned short* WRz    = (unsigned short*)(ws + off); off += (size_t)G4 * 2048 * 2 / 2;
    float*          Wcomb  = ws + off;                    off += (size_t)G4 * IN_DIM;
    float*          biasLI = ws + off;                    off += G4;
    float*          biasRI = ws + off;                    off += G4;
    unsigned short* planes = (unsigned short*)(ws + off); off += (size_t)4 * B_SZ * PSTR / 2;
    unsigned*       bar    = (unsigned*)(ws + off);       off += 64;

    unsigned short* p0h = planes;
    unsigned short* p0l = p0h + (size_t)B_SZ * PSTR;
    unsigned short* p1h = p0l + (size_t)B_SZ * PSTR;
    unsigned short* p1l = p1h + (size_t)B_SZ * PSTR;

    // --- setup ---
    gemm_f32_nn<128,128,16,8,8><<<dim3(IN_DIM/128, G4/128), 256, 0, stream>>>(
        W_ih0, W_enc, Wcomb, G4, IN_DIM, EMB);
    build_bcombI<<<G4/4, 256, 0, stream>>>(W_ih0, b_enc, b_ih0, b_hh0, biasLI);
    addvI<<<G4/256, 256, 0, stream>>>(b_ih1, b_hh1, biasRI);
    // WLz: [Wcomb(16 kf) | W_hh0(32 kf)] ; WRz: [W_ih1(32 kf) | W_hh1(32 kf)]
    swz2<<<64*48, 256, 0, stream>>>(Wcomb, IN_DIM, 16, W_hh0, HID, 48, WLz);
    swz2<<<64*64, 256, 0, stream>>>(W_ih1, HID, 32, W_hh1, HID, 64, WRz);
    hipMemsetAsync(planes, 0, (size_t)4 * B_SZ * PSTR * 2, stream);
    hipMemsetAsync(bar, 0, sizeof(unsigned), stream);

    // --- the whole recurrence in one kernel ---
    lstm_persist<<<NBLK, 512, 0, stream>>>(
        x, WLz, WRz, biasLI, biasRI,
        p0h, p0l, p1h, p1l, W_cls, b_cls, out, bar);
}